// Round 5
// baseline (41.567 us; speedup 1.0000x reference)
//
#include <hip/hip_runtime.h>

#define NN 128   // modes

// complex multiply (float2 as re,im)
__device__ __forceinline__ float2 cmul(float2 x, float2 y) {
    return make_float2(x.x * y.x - x.y * y.y, x.x * y.y + x.y * y.x);
}

// One wave (64 lanes) per output column c. Lane l holds state elements
// g = 4l..4l+3 (complex) in registers. 254 mixing layers + epilogue.
// Output: Re(T[n][c]) as float32, row-major (n, c), 128x128 = 16384 elements.
__global__ __launch_bounds__(64) void mesh_kernel(
    const float* __restrict__ theta_in,    // (128,)
    const float* __restrict__ theta_even,  // (255,128) row-major
    const float* __restrict__ theta_out,   // (128,)
    float* __restrict__ out)               // (128,128) f32 = Re(arch)
{
    const int c = blockIdx.x;   // column 0..127
    const int l = threadIdx.x;  // lane 0..63

    // MMI 2x2: [[A, iB],[iB, A]],  A = sqrt((1-IL_MMI)*(0.5+IMB)), B = sqrt((1-IL_MMI)*(0.5-IMB))
    // CROSS 2x2: [[C2, iS2],[iS2, C2]], corners = S2 = aX*sqrt(1-CT)
    const float A  = sqrtf(0.95f * 0.505f);
    const float B  = sqrtf(0.95f * 0.495f);
    const float C2 = sqrtf(0.98f * 0.01f);
    const float S2 = sqrtf(0.98f * 0.99f);

    // ---- init: column c after MMI_IN: rows 2c (A*e_in) and 2c+1 (iB*e_in) ----
    float2 v0 = make_float2(0.f, 0.f), v1 = v0, v2 = v0, v3 = v0;
    {
        float s, co;
        __sincosf(theta_in[c], &s, &co);
        float2 r0 = make_float2(A * co, A * s);        // A * e^{i th}
        float2 r1 = make_float2(-B * s, B * co);       // iB * e^{i th}
        if (l == (c >> 1)) {
            if (c & 1) { v2 = r0; v3 = r1; }           // rows 4l+2, 4l+3
            else       { v0 = r0; v1 = r1; }           // rows 4l,   4l+1
        }
    }

    // theta_even: layer j, lane l needs theta_even[j*128 + 2l], [.. + 2l+1]
    const float2* tev = (const float2*)(theta_even) + l;   // float2 index: j*64 + l
    float2 th = tev[0];

    #pragma unroll 2
    for (int j = 0; j < 254; ++j) {
        float2 th_next = tev[(j + 1) * 64];  // prefetch next layer's phases

        // diag(d_ev[j]): phases on even rows (slots 0 and 2)
        float s0, c0, s1, c1;
        __sincosf(th.x, &s0, &c0);
        __sincosf(th.y, &s1, &c1);
        v0 = cmul(v0, make_float2(c0, s0));
        v2 = cmul(v2, make_float2(c1, s1));

        // MMI_EVEN mix on (v0,v1) and (v2,v3): n0 = A v0 + iB v1 ; n1 = iB v0 + A v1
        float2 n0 = make_float2(A * v0.x - B * v1.y, A * v0.y + B * v1.x);
        float2 n1 = make_float2(A * v1.x - B * v0.y, A * v1.y + B * v0.x);
        float2 n2 = make_float2(A * v2.x - B * v3.y, A * v2.y + B * v3.x);
        float2 n3 = make_float2(A * v3.x - B * v2.y, A * v3.y + B * v2.x);
        v0 = n0; v1 = n1; v2 = n2; v3 = n3;

        if (!(j & 1)) {
            // CROSS: pairs (v1,v2) lane-local; (v3_l, v0_{l+1}) cross-lane; corners *= S2
            float2 m1 = make_float2(C2 * v1.x - S2 * v2.y, C2 * v1.y + S2 * v2.x);
            float2 m2 = make_float2(C2 * v2.x - S2 * v1.y, C2 * v2.y + S2 * v1.x);
            float nxt_re = __shfl_down(v0.x, 1);  // v0 of lane l+1
            float nxt_im = __shfl_down(v0.y, 1);
            float prv_re = __shfl_up(v3.x, 1);    // v3 of lane l-1
            float prv_im = __shfl_up(v3.y, 1);
            float2 m3 = (l == 63)
                ? make_float2(S2 * v3.x, S2 * v3.y)                       // row 255 corner
                : make_float2(C2 * v3.x - S2 * nxt_im, C2 * v3.y + S2 * nxt_re);
            float2 m0 = (l == 0)
                ? make_float2(S2 * v0.x, S2 * v0.y)                       // row 0 corner
                : make_float2(C2 * v0.x - S2 * prv_im, C2 * v0.y + S2 * prv_re);
            v0 = m0; v1 = m1; v2 = m2; v3 = m3;
        }
        th = th_next;
    }

    // j = 254: diag only (no MMI after it)
    {
        float s0, c0, s1, c1;
        __sincosf(th.x, &s0, &c0);
        __sincosf(th.y, &s1, &c1);
        v0 = cmul(v0, make_float2(c0, s0));
        v2 = cmul(v2, make_float2(c1, s1));
    }

    // MMI_OUT: out_n = A*v(2k) + iB*v(2k+1) for n = 2l, 2l+1
    float2 o0 = make_float2(A * v0.x - B * v1.y, A * v0.y + B * v1.x);
    float2 o1 = make_float2(A * v2.x - B * v3.y, A * v2.y + B * v3.x);

    // diag(d_out): row phase DOES matter for Re(.) — apply, then take real part
    float s0, c0, s1, c1;
    __sincosf(theta_out[2 * l],     &s0, &c0);
    __sincosf(theta_out[2 * l + 1], &s1, &c1);
    float re0 = o0.x * c0 - o0.y * s0;   // Re(e^{i th} * o0)
    float re1 = o1.x * c1 - o1.y * s1;

    out[(2 * l)     * NN + c] = re0;
    out[(2 * l + 1) * NN + c] = re1;
}

extern "C" void kernel_launch(void* const* d_in, const int* in_sizes, int n_in,
                              void* d_out, int out_size, void* d_ws, size_t ws_size,
                              hipStream_t stream) {
    // Identify inputs by SIZE: theta_even is the unique large (32640-elem) array;
    // the two 128-elem arrays keep relative order (theta_in before theta_out in
    // both dict order and alphabetical order).
    int ev = 0;
    for (int i = 0; i < n_in; ++i) if (in_sizes[i] > 1000) ev = i;
    int a = -1, b = -1;
    for (int i = 0; i < n_in; ++i) {
        if (i == ev) continue;
        if (a < 0) a = i; else if (b < 0) b = i;
    }
    const float* th_in  = (const float*)d_in[a];
    const float* th_ev  = (const float*)d_in[ev];
    const float* th_out = (const float*)d_in[b];
    mesh_kernel<<<dim3(NN), dim3(64), 0, stream>>>(th_in, th_ev, th_out, (float*)d_out);
}